// Round 6
// baseline (301.360 us; speedup 1.0000x reference)
//
#include <hip/hip_runtime.h>

// CTC greedy decode: B=256, T=1024, C=128, blank = C-1 = 127.
// Single kernel, wide grid + "last block per row scans" (decoupled lookback).
//
// Grid: B*16 blocks of 256 threads. Each block:
//   Stage 1 (argmax, R2-verified): 64 timesteps; 4 lanes/timestep; each lane
//     8 independent float4 loads (classes (l&3)*4 + 16*i) => 8 KB/wave in
//     flight; local argmax (first-occurrence, ascending class order) + 2-step
//     __shfl_xor reduce (min-index tie-break); result -> ws.am[row][t].
//   Stage 2: __threadfence (release) + atomicAdd(cnt[row]); the 16th block
//     of the row acquires and runs the compaction scan for the whole row:
//     int4 am loads, keep = (a!=prev && a!=blank), block prefix scan,
//     scatter kept tokens to [0,total), -1 fill on [total,T).
//
// cnt[] is zeroed every call via hipMemsetAsync (graph-capturable; ws is
// poisoned once and never re-poisoned, so no cross-call state is assumed).

constexpr int B = 256;
constexpr int T = 1024;
constexpr int C = 128;
constexpr int BLANK = C - 1;
constexpr int CHUNKS = 16;           // argmax blocks per row (64 timesteps each)

__global__ __launch_bounds__(256)
void ctc_kernel(const float* __restrict__ logits, int* __restrict__ am,
                unsigned* __restrict__ cnt, int* __restrict__ out) {
    const int tid  = threadIdx.x;
    const int lane = tid & 63;
    const int wid  = tid >> 6;              // wave 0..3
    const int row  = blockIdx.x >> 4;       // batch index
    const int chunk = blockIdx.x & 15;      // 64-timestep chunk

    // ---------------- Stage 1: argmax for this chunk ----------------
    const int t    = chunk * 64 + wid * 16 + (lane >> 2);
    const int csub = (lane & 3) * 4;

    const float* p = logits + ((size_t)row * T + t) * C + csub;

    float4 v[8];
    #pragma unroll
    for (int i = 0; i < 8; ++i)
        v[i] = *reinterpret_cast<const float4*>(p + 16 * i);

    float best = v[0].x; int bidx = csub;
    #pragma unroll
    for (int i = 0; i < 8; ++i) {
        const int cb = csub + 16 * i;
        if (i > 0 && v[i].x > best) { best = v[i].x; bidx = cb; }
        if (v[i].y > best) { best = v[i].y; bidx = cb + 1; }
        if (v[i].z > best) { best = v[i].z; bidx = cb + 2; }
        if (v[i].w > best) { best = v[i].w; bidx = cb + 3; }
    }
    #pragma unroll
    for (int off = 1; off <= 2; off <<= 1) {
        float ov = __shfl_xor(best, off, 64);
        int   oi = __shfl_xor(bidx, off, 64);
        if (ov > best || (ov == best && oi < bidx)) { best = ov; bidx = oi; }
    }
    if ((lane & 3) == 0) am[(size_t)row * T + t] = bidx;

    // ---------------- Stage 2: last block of the row scans it ----------------
    __shared__ int sLast;
    __shared__ int wsum[4];
    __syncthreads();                         // all am stores of this block issued
    if (tid == 0) {
        __threadfence();                     // release am writes device-wide
        unsigned old = atomicAdd(&cnt[row], 1u);
        sLast = (old == CHUNKS - 1) ? 1 : 0;
    }
    __syncthreads();
    if (!sLast) return;
    __threadfence();                         // acquire: see all blocks' am writes

    const int* arow = am + (size_t)row * T;
    const int4 a4   = reinterpret_cast<const int4*>(arow)[tid];
    const int aprev = (tid > 0) ? arow[4 * tid - 1] : -1;

    const int k0 = (a4.x != aprev && a4.x != BLANK) ? 1 : 0;
    const int k1 = (a4.y != a4.x  && a4.y != BLANK) ? 1 : 0;
    const int k2 = (a4.z != a4.y  && a4.z != BLANK) ? 1 : 0;
    const int k3 = (a4.w != a4.z  && a4.w != BLANK) ? 1 : 0;
    const int ksum = k0 + k1 + k2 + k3;

    // wave-inclusive prefix sum of ksum
    int scan = ksum;
    #pragma unroll
    for (int off = 1; off <= 32; off <<= 1) {
        int n = __shfl_up(scan, off, 64);
        if (lane >= off) scan += n;
    }
    if (lane == 63) wsum[wid] = scan;
    __syncthreads();

    int waveOff = 0, total = 0;
    #pragma unroll
    for (int w = 0; w < 4; ++w) {
        const int s = wsum[w];
        if (w < wid) waveOff += s;
        total += s;
    }

    int* orow = out + (size_t)row * T;
    int e = waveOff + (scan - ksum);         // exclusive prefix for this thread
    if (k0) { orow[e] = a4.x; e += 1; }
    if (k1) { orow[e] = a4.y; e += 1; }
    if (k2) { orow[e] = a4.z; e += 1; }
    if (k3) { orow[e] = a4.w; e += 1; }

    #pragma unroll
    for (int j = 0; j < 4; ++j) {
        const int idx = 4 * tid + j;
        if (idx >= total) orow[idx] = -1;    // disjoint from [0,total)
    }
}

extern "C" void kernel_launch(void* const* d_in, const int* in_sizes, int n_in,
                              void* d_out, int out_size, void* d_ws, size_t ws_size,
                              hipStream_t stream) {
    const float* logits = (const float*)d_in[0];
    int* out = (int*)d_out;
    int* am  = (int*)d_ws;                           // B*T ints = 1 MiB
    unsigned* cnt = (unsigned*)((char*)d_ws + (size_t)B * T * sizeof(int)); // B uints

    hipMemsetAsync(cnt, 0, B * sizeof(unsigned), stream);
    ctc_kernel<<<B * CHUNKS, 256, 0, stream>>>(logits, am, cnt, out);
}

// Round 7
// 24.475 us; speedup vs baseline: 12.3129x; 12.3129x over previous
//
#include <hip/hip_runtime.h>

// CTC greedy decode: B=256, T=1024, C=128, blank = C-1 = 127. Fused single kernel.
// Structure = round-4 best (26.4 us), + NONTEMPORAL streaming loads (input is
// read exactly once; nt flag reduces L2 allocation/pollution on the stream).
//
// One block per batch row, 1024 threads = 16 waves.
//
// Phase 1 (argmax, 8 sweeps of 128 timesteps, double-buffered):
//   8 lanes per timestep; lane g=tid&7 loads 4 float4 at byte offsets
//   g*16 + 128*i (i=0..3) => each wave instruction reads 8 full aligned
//   128B lines (1KB). Sweep s+1's loads are issued before consuming sweep s.
//   Local argmax over 16 elems (first-occurrence, ascending class order),
//   3-step __shfl_xor reduce in the 8-lane group (min-index tie-break),
//   result -> LDS am[t].
//
// Phase 2 (compaction, verified rounds 1-5): collapse repeats, drop blanks,
//   block-wide prefix scan, scatter kept tokens, -1 fill.
//
// NOTE (R6 post-mortem): no cross-block sync anywhere — agent-scope fences
// (__threadfence) force per-XCD L2 writeback/invalidate on gfx950 and
// collapsed streaming BW by ~30x. Keep everything block-local.

constexpr int B = 256;
constexpr int T = 1024;
constexpr int C = 128;
constexpr int BLANK = C - 1;
constexpr int SWEEPS = T / 128;      // 8

typedef float f4v __attribute__((ext_vector_type(4)));

__device__ __forceinline__ float4 nt_load4(const float* p) {
    f4v t = __builtin_nontemporal_load(reinterpret_cast<const f4v*>(p));
    float4 r; r.x = t[0]; r.y = t[1]; r.z = t[2]; r.w = t[3];
    return r;
}

__global__ __launch_bounds__(1024, 4)
void ctc_fused_kernel(const float* __restrict__ logits, int* __restrict__ out) {
    const int b    = blockIdx.x;
    const int tid  = threadIdx.x;
    const int lane = tid & 63;
    const int wid  = tid >> 6;          // wave id 0..15

    __shared__ int am[T];
    __shared__ int wsum[16];

    const float* row = logits + (size_t)b * T * C;

    // ---------------- Phase 1: argmax per timestep ----------------
    const int g     = tid & 7;          // lane within 8-lane group
    const int tsub  = tid >> 3;         // timestep within sweep (0..127)
    const int csub  = g * 4;            // class base: csub + 32*i, i=0..3

    float4 buf[2][4];
    {   // prologue: sweep 0
        const float* p = row + (size_t)tsub * C + csub;
        #pragma unroll
        for (int i = 0; i < 4; ++i)
            buf[0][i] = nt_load4(p + 32 * i);
    }

    #pragma unroll
    for (int s = 0; s < SWEEPS; ++s) {
        if (s + 1 < SWEEPS) {           // issue next sweep's loads first
            const float* p = row + (size_t)((s + 1) * 128 + tsub) * C + csub;
            #pragma unroll
            for (int i = 0; i < 4; ++i)
                buf[(s + 1) & 1][i] = nt_load4(p + 32 * i);
        }

        // consume sweep s: local argmax over 16 elems, first-occurrence.
        const float4* v = buf[s & 1];
        float best = v[0].x; int bidx = csub;
        #pragma unroll
        for (int i = 0; i < 4; ++i) {
            const int cb = csub + 32 * i;
            if (i > 0 && v[i].x > best) { best = v[i].x; bidx = cb; }
            if (v[i].y > best) { best = v[i].y; bidx = cb + 1; }
            if (v[i].z > best) { best = v[i].z; bidx = cb + 2; }
            if (v[i].w > best) { best = v[i].w; bidx = cb + 3; }
        }

        // reduce across the 8 lanes of this timestep (xor 1,2,4 stay in-group).
        #pragma unroll
        for (int off = 1; off <= 4; off <<= 1) {
            float ov = __shfl_xor(best, off, 64);
            int   oi = __shfl_xor(bidx, off, 64);
            if (ov > best || (ov == best && oi < bidx)) { best = ov; bidx = oi; }
        }

        if (g == 0) am[s * 128 + tsub] = bidx;
    }
    __syncthreads();

    // ---------------- Phase 2: compaction ----------------
    const int a    = am[tid];
    const int prev = (tid > 0) ? am[tid - 1] : -1;
    const int keep = (a != prev && a != BLANK) ? 1 : 0;

    // wave-inclusive prefix sum of keep
    int scan = keep;
    #pragma unroll
    for (int off = 1; off <= 32; off <<= 1) {
        int n = __shfl_up(scan, off, 64);
        if (lane >= off) scan += n;
    }
    if (lane == 63) wsum[wid] = scan;
    __syncthreads();

    int waveOff = 0, total = 0;
    #pragma unroll
    for (int w = 0; w < 16; ++w) {
        const int s = wsum[w];
        if (w < wid) waveOff += s;
        total += s;
    }

    int* orow = out + (size_t)b * T;
    if (keep) orow[waveOff + scan - 1] = a;   // positions [0, total)
    if (tid >= total) orow[tid] = -1;         // positions [total, T) — disjoint
}

extern "C" void kernel_launch(void* const* d_in, const int* in_sizes, int n_in,
                              void* d_out, int out_size, void* d_ws, size_t ws_size,
                              hipStream_t stream) {
    const float* logits = (const float*)d_in[0];
    int* out = (int*)d_out;
    ctc_fused_kernel<<<B, 1024, 0, stream>>>(logits, out);
}